// Round 1
// baseline (2797.088 us; speedup 1.0000x reference)
//
#include <hip/hip_runtime.h>
#include <cstdint>
#include <cstddef>

#define S_LEN 2048
#define BATCH 2
#define DMODEL 1024
#define NH 16
#define NKV 4
#define HDIM 64
#define NTOK 4096
#define IDIM 3584
#define NEXP 4
#define WINSZ 512
#define EPSV 1e-5f
#define LIMV 7.0f

typedef unsigned short u16;
typedef unsigned int u32;
typedef __bf16 bf16x8 __attribute__((ext_vector_type(8)));
typedef float f32x4 __attribute__((ext_vector_type(4)));
typedef u32 u32x4 __attribute__((ext_vector_type(4)));
typedef u16 u16x4 __attribute__((ext_vector_type(4)));

__device__ __forceinline__ u16 f2b(float f) {
  union { float f; u32 u; } v; v.f = f;
  return (u16)((v.u + 0x7fffu + ((v.u >> 16) & 1u)) >> 16);
}
__device__ __forceinline__ float b2f(u16 h) {
  union { u32 u; float f; } v; v.u = ((u32)h) << 16; return v.f;
}
__device__ __forceinline__ float wave_sum(float x) {
#pragma unroll
  for (int o = 32; o > 0; o >>= 1) x += __shfl_xor(x, o);
  return x;
}
__device__ __forceinline__ float wave_max(float x) {
#pragma unroll
  for (int o = 32; o > 0; o >>= 1) x = fmaxf(x, __shfl_xor(x, o));
  return x;
}

// ---------------- init ----------------
__global__ void k_init(int* cnt) {
  if (threadIdx.x < NEXP) cnt[threadIdx.x] = 0;
}

// ---------------- weight conversion (fp32 -> bf16, optionally split hi/lo) ----
struct CvtArgs {
  const float* src[10];
  u16* dh[10];
  u16* dl[10];
  int n4[10];
};
__global__ __launch_bounds__(256) void k_convert(CvtArgs a) {
  int ai = blockIdx.y;
  const f32x4* s = (const f32x4*)a.src[ai];
  u16* dh = a.dh[ai];
  u16* dl = a.dl[ai];
  int n4 = a.n4[ai];
  for (int i = blockIdx.x * 256 + threadIdx.x; i < n4; i += gridDim.x * 256) {
    f32x4 v = s[i];
    u16x4 h;
    h.x = f2b(v.x); h.y = f2b(v.y); h.z = f2b(v.z); h.w = f2b(v.w);
    ((u16x4*)dh)[i] = h;
    if (dl) {
      u16x4 lo;
      lo.x = f2b(v.x - b2f(h.x)); lo.y = f2b(v.y - b2f(h.y));
      lo.z = f2b(v.z - b2f(h.z)); lo.w = f2b(v.w - b2f(h.w));
      ((u16x4*)dl)[i] = lo;
    }
  }
}

// ---------------- rms over D=1024, write split bf16 ----------------
__global__ __launch_bounds__(256) void k_rms_split(const float* __restrict__ x,
                                                   const float* __restrict__ w,
                                                   u16* __restrict__ oh, u16* __restrict__ ol) {
  int row = blockIdx.x;
  int t = threadIdx.x;
  const f32x4* xr = (const f32x4*)(x + (size_t)row * DMODEL);
  f32x4 v = xr[t];
  float ss = v.x * v.x + v.y * v.y + v.z * v.z + v.w * v.w;
  ss = wave_sum(ss);
  __shared__ float red[4];
  int wid = t >> 6;
  if ((t & 63) == 0) red[wid] = ss;
  __syncthreads();
  float tot = red[0] + red[1] + red[2] + red[3];
  float r = rsqrtf(tot * (1.0f / DMODEL) + EPSV);
  f32x4 wv = ((const f32x4*)w)[t];
  float y0 = v.x * r * wv.x, y1 = v.y * r * wv.y, y2 = v.z * r * wv.z, y3 = v.w * r * wv.w;
  u16x4 h; h.x = f2b(y0); h.y = f2b(y1); h.z = f2b(y2); h.w = f2b(y3);
  u16x4 lo; lo.x = f2b(y0 - b2f(h.x)); lo.y = f2b(y1 - b2f(h.y));
  lo.z = f2b(y2 - b2f(h.z)); lo.w = f2b(y3 - b2f(h.w));
  ((u16x4*)(oh + (size_t)row * DMODEL))[t] = h;
  ((u16x4*)(ol + (size_t)row * DMODEL))[t] = lo;
}

// ---------------- per-head rms + rope on q/k, copy v, all fp32 ----------------
__global__ __launch_bounds__(256) void k_qkprep(const float* __restrict__ qkv,
                                                const float* __restrict__ cosb,
                                                const float* __restrict__ sinb,
                                                const float* __restrict__ qw,
                                                const float* __restrict__ kw,
                                                float* __restrict__ qf, float* __restrict__ kf,
                                                float* __restrict__ vf) {
  int t = blockIdx.x;  // token
  int b = t / S_LEN, s = t - b * S_LEN;
  int wid = threadIdx.x >> 6, l = threadIdx.x & 63;
  const float* row = qkv + (size_t)t * 1536;
  float c = cosb[s * 64 + l], sn = sinb[s * 64 + l];
#pragma unroll
  for (int ii = 0; ii < 6; ii++) {
    int u = wid + 4 * ii;
    if (u < 16) {
      float v = row[u * 64 + l];
      float ss = wave_sum(v * v);
      float r = rsqrtf(ss * (1.0f / 64.0f) + EPSV);
      float vn = v * r * qw[l];
      float p = __shfl_xor(vn, 32);
      float o = (l < 32) ? (vn * c - p * sn) : (vn * c + p * sn);
      qf[(((size_t)b * NH + u) * S_LEN + s) * 64 + l] = o;
    } else if (u < 20) {
      int kv = u - 16;
      float v = row[1024 + kv * 64 + l];
      float ss = wave_sum(v * v);
      float r = rsqrtf(ss * (1.0f / 64.0f) + EPSV);
      float vn = v * r * kw[l];
      float p = __shfl_xor(vn, 32);
      float o = (l < 32) ? (vn * c - p * sn) : (vn * c + p * sn);
      kf[(((size_t)b * NKV + kv) * S_LEN + s) * 64 + l] = o;
    } else {
      int kv = u - 20;
      vf[(((size_t)b * NKV + kv) * S_LEN + s) * 64 + l] = row[1280 + kv * 64 + l];
    }
  }
}

// ---------------- sliding-window attention with sink, fp32, 4 queries/wave ----
__global__ __launch_bounds__(256) void k_attn(const float* __restrict__ qf,
                                              const float* __restrict__ kf,
                                              const float* __restrict__ vf,
                                              const float* __restrict__ sinks,
                                              u16* __restrict__ oh, u16* __restrict__ ol) {
  int bid = blockIdx.x;            // B*H*(S/16) = 4096
  int ib = (bid & 127) * 16;
  int bh = bid >> 7;               // b*16 + h
  int h = bh & 15, b = bh >> 4;
  int wid = threadIdx.x >> 6, l = threadIdx.x & 63;
  int i0 = ib + wid * 4;
  const float* qbase = qf + ((size_t)bh * S_LEN) * 64;
  int kvh = h >> 2;
  const float* kbase = kf + (((size_t)b * NKV + kvh) * S_LEN) * 64;
  const float* vbase = vf + (((size_t)b * NKV + kvh) * S_LEN) * 64;

  __shared__ float q_lds[16][64];
  __shared__ float p_lds[4][64][4];

  float sk = sinks[h];
  float m[4], lsum[4], acc[4];
#pragma unroll
  for (int q = 0; q < 4; q++) { m[q] = sk; lsum[q] = 1.0f; acc[q] = 0.0f; }
#pragma unroll
  for (int q = 0; q < 4; q++)
    q_lds[wid * 4 + q][l] = qbase[((size_t)(i0 + q)) * 64 + l] * 0.125f;

  int jlow = i0 - (WINSZ - 1);
  int j0start = (jlow > 0) ? (jlow & ~63) : 0;

  for (int j0 = j0start; j0 <= i0 + 3; j0 += 64) {
    int j = j0 + l;
    int jc = j < S_LEN ? j : (S_LEN - 1);
    const float* kr = kbase + (size_t)jc * 64;
    float s[4] = {0.f, 0.f, 0.f, 0.f};
#pragma unroll
    for (int d0 = 0; d0 < 16; d0++) {
      f32x4 kv4 = ((const f32x4*)kr)[d0];
#pragma unroll
      for (int q = 0; q < 4; q++) {
        f32x4 qv4 = *((const f32x4*)&q_lds[wid * 4 + q][d0 * 4]);
        s[q] += kv4.x * qv4.x + kv4.y * qv4.y + kv4.z * qv4.z + kv4.w * qv4.w;
      }
    }
    float pl[4];
#pragma unroll
    for (int q = 0; q < 4; q++) {
      int iq = i0 + q;
      bool ok = (j <= iq) && (j > iq - WINSZ);
      float sq = ok ? s[q] : -1e30f;
      float cm = wave_max(sq);
      float mn = fmaxf(m[q], cm);
      float sc = __expf(m[q] - mn);
      float p = __expf(sq - mn);
      float ps = wave_sum(p);
      lsum[q] = lsum[q] * sc + ps;
      acc[q] *= sc;
      m[q] = mn;
      pl[q] = p;
    }
    f32x4 pv = {pl[0], pl[1], pl[2], pl[3]};
    *((f32x4*)&p_lds[wid][l][0]) = pv;
#pragma unroll 8
    for (int jj = 0; jj < 64; jj++) {
      int jv = j0 + jj; jv = jv < S_LEN ? jv : (S_LEN - 1);
      float vv = vbase[(size_t)jv * 64 + l];
      f32x4 p4 = *((const f32x4*)&p_lds[wid][jj][0]);
      acc[0] += p4.x * vv; acc[1] += p4.y * vv; acc[2] += p4.z * vv; acc[3] += p4.w * vv;
    }
  }
#pragma unroll
  for (int q = 0; q < 4; q++) {
    float o = acc[q] / lsum[q];
    size_t ti = ((size_t)b * S_LEN + i0 + q) * (NH * HDIM) + h * 64 + l;
    u16 hi = f2b(o);
    oh[ti] = hi;
    ol[ti] = f2b(o - b2f(hi));
  }
}

// ---------------- routing: rms(h1) -> m_b bf16, gate softmax top2, idx lists --
__global__ __launch_bounds__(256) void k_routing(const float* __restrict__ h1,
                                                 const float* __restrict__ pw,
                                                 const float* __restrict__ gw,
                                                 u16* __restrict__ mb, float* __restrict__ wd,
                                                 int* __restrict__ cnt, int* __restrict__ idxb) {
  int row = blockIdx.x;
  int t = threadIdx.x;
  int wid = t >> 6;
  const f32x4* xr = (const f32x4*)(h1 + (size_t)row * DMODEL);
  f32x4 v = xr[t];
  float ss = wave_sum(v.x * v.x + v.y * v.y + v.z * v.z + v.w * v.w);
  __shared__ float red[4];
  __shared__ float redp[4][4];
  if ((t & 63) == 0) red[wid] = ss;
  __syncthreads();
  float tot = red[0] + red[1] + red[2] + red[3];
  float r = rsqrtf(tot * (1.0f / DMODEL) + EPSV);
  f32x4 w4 = ((const f32x4*)pw)[t];
  float m0 = v.x * r * w4.x, m1 = v.y * r * w4.y, m2 = v.z * r * w4.z, m3 = v.w * r * w4.w;
  u16x4 hb; hb.x = f2b(m0); hb.y = f2b(m1); hb.z = f2b(m2); hb.w = f2b(m3);
  ((u16x4*)(mb + (size_t)row * DMODEL))[t] = hb;
#pragma unroll
  for (int e = 0; e < NEXP; e++) {
    f32x4 g4 = ((const f32x4*)(gw + (size_t)e * DMODEL))[t];
    float pe = wave_sum(m0 * g4.x + m1 * g4.y + m2 * g4.z + m3 * g4.w);
    if ((t & 63) == 0) redp[wid][e] = pe;
  }
  __syncthreads();
  if (t == 0) {
    float lg[4];
#pragma unroll
    for (int e = 0; e < NEXP; e++) lg[e] = redp[0][e] + redp[1][e] + redp[2][e] + redp[3][e];
    float mx = fmaxf(fmaxf(lg[0], lg[1]), fmaxf(lg[2], lg[3]));
    float ex[4], sm = 0.f;
#pragma unroll
    for (int e = 0; e < NEXP; e++) { ex[e] = expf(lg[e] - mx); sm += ex[e]; }
    int i1 = 0;
#pragma unroll
    for (int e = 1; e < NEXP; e++) if (lg[e] > lg[i1]) i1 = e;
    int i2 = -1;
#pragma unroll
    for (int e = 0; e < NEXP; e++) if (e != i1 && (i2 < 0 || lg[e] > lg[i2])) i2 = e;
    float p1 = ex[i1] / sm, p2 = ex[i2] / sm;
    float s2 = p1 + p2 + 1e-20f;
    float wrow[4] = {0.f, 0.f, 0.f, 0.f};
    wrow[i1] = p1 / s2; wrow[i2] = p2 / s2;
#pragma unroll
    for (int e = 0; e < NEXP; e++) wd[(size_t)row * NEXP + e] = wrow[e];
    int pos1 = atomicAdd(&cnt[i1], 1);
    idxb[i1 * NTOK + pos1] = row;
    int pos2 = atomicAdd(&cnt[i2], 1);
    idxb[i2 * NTOK + pos2] = row;
  }
}

// ---------------- MFMA GEMM: C[M,N] = A[M,K] @ Bw[N,K]^T ----------------
// 128x128 tile, BK=32, 4 waves, 16x16x32 bf16 mfma. Optional split (hi/lo) for
// ~fp23 accuracy; optional A-row gather via idx list; several fused epilogues.
constexpr int EPI_STORE = 0;  // outF[r*ldc + col0 + c] = v
constexpr int EPI_H1 = 1;     // outF[r*ldc+c] = v + addsrc[r*ldc+c]
constexpr int EPI_G = 2;      // outU[r*N+c] = bf16(v)
constexpr int EPI_ACT = 3;    // outU[r*N+c] = bf16(silu(min(g,7))*clip(v,+-7))
constexpr int EPI_DOWNM = 4;  // outF[idx[r]*ldc+c] += wd[idx[r]*4+eid]*v

template <int EPI, bool SPLIT>
__global__ __launch_bounds__(256) void k_gemm(
    const u16* __restrict__ Ah, const u16* __restrict__ Al,
    const u16* __restrict__ Bh, const u16* __restrict__ Bl,
    int M, int N, int K, int lda, int ldb,
    float* __restrict__ outF, int ldc, int col0,
    const float* __restrict__ addsrc,
    u16* __restrict__ outU, const u16* __restrict__ gsrc,
    const int* __restrict__ gidx, const int* __restrict__ cntp,
    int eid, const float* __restrict__ wdv) {
  constexpr int NSP = SPLIT ? 2 : 1;
  __shared__ u16 As[NSP * 128 * 32];
  __shared__ u16 Bs[NSP * 128 * 32];
  int tm = blockIdx.y, tn = blockIdx.x;
  int Meff = cntp ? *cntp : M;
  if (tm * 128 >= Meff) return;

  int t = threadIdx.x;
  int wid = t >> 6, l = t & 63;
  int wr = wid >> 1, wc = wid & 1;
  constexpr bool GA = (EPI == EPI_G || EPI == EPI_ACT);

  size_t a0off, a1off;
  if (GA && gidx) {
    int p0 = tm * 128 + (t >> 2);
    int p1 = p0 + 64;
    int t0 = (p0 < Meff) ? gidx[p0] : 0;
    int t1 = (p1 < Meff) ? gidx[p1] : 0;
    a0off = (size_t)t0 * lda + (t & 3) * 8;
    a1off = (size_t)t1 * lda + (t & 3) * 8;
  } else {
    a0off = (size_t)(tm * 128 + (t >> 2)) * lda + (t & 3) * 8;
    a1off = a0off + (size_t)64 * lda;
  }
  size_t b0off = (size_t)(tn * 128 + (t >> 2)) * ldb + (t & 3) * 8;
  size_t b1off = b0off + (size_t)64 * ldb;

  f32x4 acc[4][4];
#pragma unroll
  for (int i = 0; i < 4; i++)
#pragma unroll
    for (int j = 0; j < 4; j++) acc[i][j] = (f32x4){0.f, 0.f, 0.f, 0.f};

  int arow = wr * 64 + (l & 15);
  int brow = wc * 64 + (l & 15);
  int koff = (l >> 4) * 8;
  u32x4* As4 = (u32x4*)As;
  u32x4* Bs4 = (u32x4*)Bs;

  for (int k0 = 0; k0 < K; k0 += 32) {
    u32x4 va0 = *(const u32x4*)(Ah + a0off + k0);
    u32x4 va1 = *(const u32x4*)(Ah + a1off + k0);
    u32x4 vb0 = *(const u32x4*)(Bh + b0off + k0);
    u32x4 vb1 = *(const u32x4*)(Bh + b1off + k0);
    u32x4 va0l, va1l, vb0l, vb1l;
    if constexpr (SPLIT) {
      va0l = *(const u32x4*)(Al + a0off + k0);
      va1l = *(const u32x4*)(Al + a1off + k0);
      vb0l = *(const u32x4*)(Bl + b0off + k0);
      vb1l = *(const u32x4*)(Bl + b1off + k0);
    }
    __syncthreads();
    As4[t] = va0; As4[256 + t] = va1;
    Bs4[t] = vb0; Bs4[256 + t] = vb1;
    if constexpr (SPLIT) {
      As4[512 + t] = va0l; As4[768 + t] = va1l;
      Bs4[512 + t] = vb0l; Bs4[768 + t] = vb1l;
    }
    __syncthreads();
    bf16x8 af[NSP][4], bf[NSP][4];
#pragma unroll
    for (int mm = 0; mm < 4; mm++) {
      af[0][mm] = *(const bf16x8*)&As[(arow + mm * 16) * 32 + koff];
      bf[0][mm] = *(const bf16x8*)&Bs[(brow + mm * 16) * 32 + koff];
      if constexpr (SPLIT) {
        af[1][mm] = *(const bf16x8*)&As[128 * 32 + (arow + mm * 16) * 32 + koff];
        bf[1][mm] = *(const bf16x8*)&Bs[128 * 32 + (brow + mm * 16) * 32 + koff];
      }
    }
#pragma unroll
    for (int mi = 0; mi < 4; mi++)
#pragma unroll
      for (int ni = 0; ni < 4; ni++) {
        acc[mi][ni] = __builtin_amdgcn_mfma_f32_16x16x32_bf16(af[0][mi], bf[0][ni], acc[mi][ni], 0, 0, 0);
        if constexpr (SPLIT) {
          acc[mi][ni] = __builtin_amdgcn_mfma_f32_16x16x32_bf16(af[0][mi], bf[1][ni], acc[mi][ni], 0, 0, 0);
          acc[mi][ni] = __builtin_amdgcn_mfma_f32_16x16x32_bf16(af[1][mi], bf[0][ni], acc[mi][ni], 0, 0, 0);
        }
      }
  }

  int rb = tm * 128 + wr * 64 + ((l >> 4) << 2);
  int cb = tn * 128 + wc * 64 + (l & 15);
#pragma unroll
  for (int mi = 0; mi < 4; mi++) {
#pragma unroll
    for (int j = 0; j < 4; j++) {
      int r = rb + mi * 16 + j;
#pragma unroll
      for (int ni = 0; ni < 4; ni++) {
        int c = cb + ni * 16;
        float v = acc[mi][ni][j];
        if constexpr (EPI == EPI_STORE) {
          outF[(size_t)r * ldc + col0 + c] = v;
        } else if constexpr (EPI == EPI_H1) {
          size_t o = (size_t)r * ldc + c;
          outF[o] = v + addsrc[o];
        } else if constexpr (EPI == EPI_G) {
          outU[(size_t)r * N + c] = f2b(v);
        } else if constexpr (EPI == EPI_ACT) {
          float g = b2f(gsrc[(size_t)r * N + c]);
          float gm = fminf(g, LIMV);
          float um = fminf(fmaxf(v, -LIMV), LIMV);
          float a = gm / (1.0f + __expf(-gm)) * um;
          outU[(size_t)r * N + c] = f2b(a);
        } else {  // EPI_DOWNM
          if (r < Meff) {
            int tok = gidx[r];
            float w = wdv[(size_t)tok * NEXP + eid];
            size_t o = (size_t)tok * ldc + c;
            outF[o] += w * v;
          }
        }
      }
    }
  }
}

// ---------------- final residual add ----------------
__global__ __launch_bounds__(256) void k_final(const float* __restrict__ h1,
                                               const float* __restrict__ y,
                                               float* __restrict__ out) {
  int i = blockIdx.x * 256 + threadIdx.x;
  f32x4 a = ((const f32x4*)h1)[i];
  f32x4 b = ((const f32x4*)y)[i];
  f32x4 r = {a.x + b.x, a.y + b.y, a.z + b.z, a.w + b.w};
  ((f32x4*)out)[i] = r;
}

// ---------------- host ----------------
extern "C" void kernel_launch(void* const* d_in, const int* in_sizes, int n_in,
                              void* d_out, int out_size, void* d_ws, size_t ws_size,
                              hipStream_t stream) {
  (void)in_sizes; (void)n_in; (void)out_size; (void)ws_size;
  const float* x = (const float*)d_in[0];
  const float* cosb = (const float*)d_in[1];
  const float* sinb = (const float*)d_in[2];
  const float* anw = (const float*)d_in[3];
  const float* pnw = (const float*)d_in[4];
  const float* qnw = (const float*)d_in[5];
  const float* knw = (const float*)d_in[6];
  const float* wq = (const float*)d_in[7];
  const float* wk = (const float*)d_in[8];
  const float* wv = (const float*)d_in[9];
  const float* wo = (const float*)d_in[10];
  const float* sinks = (const float*)d_in[11];
  const float* gw = (const float*)d_in[12];
  const float* egw = (const float*)d_in[13];
  const float* euw = (const float*)d_in[14];
  const float* edw = (const float*)d_in[15];
  const float* sgw = (const float*)d_in[16];
  const float* suw = (const float*)d_in[17];
  const float* sdw = (const float*)d_in[18];
  float* out = (float*)d_out;

  char* ws = (char*)d_ws;
  size_t off = 0;
  auto alloc = [&](size_t bytes) -> char* {
    char* p = ws + off;
    off += (bytes + 255) & ~(size_t)255;
    return p;
  };
  u16* wqh = (u16*)alloc(1048576 * 2); u16* wql = (u16*)alloc(1048576 * 2);
  u16* wkh = (u16*)alloc(262144 * 2);  u16* wkl = (u16*)alloc(262144 * 2);
  u16* wvh = (u16*)alloc(262144 * 2);  u16* wvl = (u16*)alloc(262144 * 2);
  u16* woh = (u16*)alloc(1048576 * 2); u16* wol = (u16*)alloc(1048576 * 2);
  u16* egb = (u16*)alloc((size_t)14680064 * 2);
  u16* eub = (u16*)alloc((size_t)14680064 * 2);
  u16* edb = (u16*)alloc((size_t)14680064 * 2);
  u16* sgb = (u16*)alloc((size_t)3670016 * 2);
  u16* sub = (u16*)alloc((size_t)3670016 * 2);
  u16* sdb = (u16*)alloc((size_t)3670016 * 2);
  u16* hinh = (u16*)alloc((size_t)NTOK * DMODEL * 2);
  u16* hinl = (u16*)alloc((size_t)NTOK * DMODEL * 2);
  u16* attnh = (u16*)alloc((size_t)NTOK * DMODEL * 2);
  u16* attnl = (u16*)alloc((size_t)NTOK * DMODEL * 2);
  float* h1 = (float*)alloc((size_t)NTOK * DMODEL * 4);
  u16* mb = (u16*)alloc((size_t)NTOK * DMODEL * 2);
  float* ybuf = (float*)alloc((size_t)NTOK * DMODEL * 4);
  float* wdbuf = (float*)alloc((size_t)NTOK * NEXP * 4);
  int* cnt = (int*)alloc(256);
  int* idxb = (int*)alloc((size_t)NEXP * NTOK * 4);
  // overlapped region: attention-path scratch then MoE scratch
  char* regA = alloc((size_t)58720256);
  float* qkvb = (float*)regA;                       // 4096 x 1536 fp32
  float* qf = (float*)(regA + 25165824);            // [B][H][S][64] fp32
  float* kf = (float*)(regA + 41943040);            // [B][KV][S][64] fp32
  float* vf = (float*)(regA + 46137344);            // [B][KV][S][64] fp32
  u16* gbuf = (u16*)regA;                           // 4096 x 3584 bf16
  u16* actb = (u16*)(regA + 29360128);              // 4096 x 3584 bf16

  k_init<<<1, 64, 0, stream>>>(cnt);

  CvtArgs ca;
  const float* srcs[10] = {wq, wk, wv, wo, egw, euw, edw, sgw, suw, sdw};
  u16* dhs[10] = {wqh, wkh, wvh, woh, egb, eub, edb, sgb, sub, sdb};
  u16* dls[10] = {wql, wkl, wvl, wol, nullptr, nullptr, nullptr, nullptr, nullptr, nullptr};
  int ns[10] = {1048576, 262144, 262144, 1048576, 14680064, 14680064, 14680064,
                3670016, 3670016, 3670016};
  for (int i = 0; i < 10; i++) {
    ca.src[i] = srcs[i]; ca.dh[i] = dhs[i]; ca.dl[i] = dls[i]; ca.n4[i] = ns[i] / 4;
  }
  k_convert<<<dim3(2048, 10), 256, 0, stream>>>(ca);

  k_rms_split<<<NTOK, 256, 0, stream>>>(x, anw, hinh, hinl);

  // qkv projections (split precision), write fp32 into qkvb (ldc=1536)
  k_gemm<EPI_STORE, true><<<dim3(8, 32), 256, 0, stream>>>(
      hinh, hinl, wqh, wql, NTOK, 1024, 1024, 1024, 1024,
      qkvb, 1536, 0, nullptr, nullptr, nullptr, nullptr, nullptr, 0, nullptr);
  k_gemm<EPI_STORE, true><<<dim3(2, 32), 256, 0, stream>>>(
      hinh, hinl, wkh, wkl, NTOK, 256, 1024, 1024, 1024,
      qkvb, 1536, 1024, nullptr, nullptr, nullptr, nullptr, nullptr, 0, nullptr);
  k_gemm<EPI_STORE, true><<<dim3(2, 32), 256, 0, stream>>>(
      hinh, hinl, wvh, wvl, NTOK, 256, 1024, 1024, 1024,
      qkvb, 1536, 1280, nullptr, nullptr, nullptr, nullptr, nullptr, 0, nullptr);

  k_qkprep<<<NTOK, 256, 0, stream>>>(qkvb, cosb, sinb, qnw, knw, qf, kf, vf);
  k_attn<<<4096, 256, 0, stream>>>(qf, kf, vf, sinks, attnh, attnl);

  // out-proj + residual -> h1 (split precision)
  k_gemm<EPI_H1, true><<<dim3(8, 32), 256, 0, stream>>>(
      attnh, attnl, woh, wol, NTOK, 1024, 1024, 1024, 1024,
      h1, 1024, 0, x, nullptr, nullptr, nullptr, nullptr, 0, nullptr);

  k_routing<<<NTOK, 256, 0, stream>>>(h1, pnw, gw, mb, wdbuf, cnt, idxb);

  // shared FFN
  k_gemm<EPI_G, false><<<dim3(28, 32), 256, 0, stream>>>(
      mb, nullptr, sgb, nullptr, NTOK, IDIM, 1024, 1024, 1024,
      nullptr, 0, 0, nullptr, gbuf, nullptr, nullptr, nullptr, 0, nullptr);
  k_gemm<EPI_ACT, false><<<dim3(28, 32), 256, 0, stream>>>(
      mb, nullptr, sub, nullptr, NTOK, IDIM, 1024, 1024, 1024,
      nullptr, 0, 0, nullptr, actb, gbuf, nullptr, nullptr, 0, nullptr);
  k_gemm<EPI_STORE, false><<<dim3(8, 32), 256, 0, stream>>>(
      actb, nullptr, sdb, nullptr, NTOK, 1024, IDIM, IDIM, IDIM,
      ybuf, 1024, 0, nullptr, nullptr, nullptr, nullptr, nullptr, 0, nullptr);

  // experts (gathered top-2)
  for (int e = 0; e < NEXP; e++) {
    const u16* beg = egb + (size_t)e * IDIM * DMODEL;
    const u16* beu = eub + (size_t)e * IDIM * DMODEL;
    const u16* bed = edb + (size_t)e * DMODEL * IDIM;
    k_gemm<EPI_G, false><<<dim3(28, 32), 256, 0, stream>>>(
        mb, nullptr, beg, nullptr, NTOK, IDIM, 1024, 1024, 1024,
        nullptr, 0, 0, nullptr, gbuf, nullptr, idxb + e * NTOK, cnt + e, e, nullptr);
    k_gemm<EPI_ACT, false><<<dim3(28, 32), 256, 0, stream>>>(
        mb, nullptr, beu, nullptr, NTOK, IDIM, 1024, 1024, 1024,
        nullptr, 0, 0, nullptr, actb, gbuf, idxb + e * NTOK, cnt + e, e, nullptr);
    k_gemm<EPI_DOWNM, false><<<dim3(8, 32), 256, 0, stream>>>(
        actb, nullptr, bed, nullptr, NTOK, 1024, IDIM, IDIM, IDIM,
        ybuf, 1024, 0, nullptr, nullptr, nullptr, idxb + e * NTOK, cnt + e, e, wdbuf);
  }

  k_final<<<4096, 256, 0, stream>>>(h1, ybuf, out);
}

// Round 2
// 1284.470 us; speedup vs baseline: 2.1776x; 2.1776x over previous
//
#include <hip/hip_runtime.h>
#include <cstdint>
#include <cstddef>

#define S_LEN 2048
#define BATCH 2
#define DMODEL 1024
#define NH 16
#define NKV 4
#define HDIM 64
#define NTOK 4096
#define IDIM 3584
#define NEXP 4
#define WINSZ 512
#define EPSV 1e-5f
#define LIMV 7.0f

typedef unsigned short u16;
typedef unsigned int u32;
typedef __bf16 bf16x8 __attribute__((ext_vector_type(8)));
typedef float f32x4 __attribute__((ext_vector_type(4)));
typedef u32 u32x4 __attribute__((ext_vector_type(4)));
typedef u16 u16x4 __attribute__((ext_vector_type(4)));

__device__ __forceinline__ u16 f2b(float f) {
  union { float f; u32 u; } v; v.f = f;
  return (u16)((v.u + 0x7fffu + ((v.u >> 16) & 1u)) >> 16);
}
__device__ __forceinline__ float b2f(u16 h) {
  union { u32 u; float f; } v; v.u = ((u32)h) << 16; return v.f;
}
__device__ __forceinline__ float wave_sum(float x) {
#pragma unroll
  for (int o = 32; o > 0; o >>= 1) x += __shfl_xor(x, o);
  return x;
}

// ---------------- init ----------------
__global__ void k_init(int* cnt) {
  if (threadIdx.x < NEXP) cnt[threadIdx.x] = 0;
}

// ---------------- weight conversion (fp32 -> bf16, optionally split hi/lo) ----
struct CvtArgs {
  const float* src[10];
  u16* dh[10];
  u16* dl[10];
  int n4[10];
};
__global__ __launch_bounds__(256) void k_convert(CvtArgs a) {
  int ai = blockIdx.y;
  const f32x4* s = (const f32x4*)a.src[ai];
  u16* dh = a.dh[ai];
  u16* dl = a.dl[ai];
  int n4 = a.n4[ai];
  for (int i = blockIdx.x * 256 + threadIdx.x; i < n4; i += gridDim.x * 256) {
    f32x4 v = s[i];
    u16x4 h;
    h.x = f2b(v.x); h.y = f2b(v.y); h.z = f2b(v.z); h.w = f2b(v.w);
    ((u16x4*)dh)[i] = h;
    if (dl) {
      u16x4 lo;
      lo.x = f2b(v.x - b2f(h.x)); lo.y = f2b(v.y - b2f(h.y));
      lo.z = f2b(v.z - b2f(h.z)); lo.w = f2b(v.w - b2f(h.w));
      ((u16x4*)dl)[i] = lo;
    }
  }
}

// ---------------- rms over D=1024, write split bf16 ----------------
__global__ __launch_bounds__(256) void k_rms_split(const float* __restrict__ x,
                                                   const float* __restrict__ w,
                                                   u16* __restrict__ oh, u16* __restrict__ ol) {
  int row = blockIdx.x;
  int t = threadIdx.x;
  const f32x4* xr = (const f32x4*)(x + (size_t)row * DMODEL);
  f32x4 v = xr[t];
  float ss = v.x * v.x + v.y * v.y + v.z * v.z + v.w * v.w;
  ss = wave_sum(ss);
  __shared__ float red[4];
  int wid = t >> 6;
  if ((t & 63) == 0) red[wid] = ss;
  __syncthreads();
  float tot = red[0] + red[1] + red[2] + red[3];
  float r = rsqrtf(tot * (1.0f / DMODEL) + EPSV);
  f32x4 wv = ((const f32x4*)w)[t];
  float y0 = v.x * r * wv.x, y1 = v.y * r * wv.y, y2 = v.z * r * wv.z, y3 = v.w * r * wv.w;
  u16x4 h; h.x = f2b(y0); h.y = f2b(y1); h.z = f2b(y2); h.w = f2b(y3);
  u16x4 lo; lo.x = f2b(y0 - b2f(h.x)); lo.y = f2b(y1 - b2f(h.y));
  lo.z = f2b(y2 - b2f(h.z)); lo.w = f2b(y3 - b2f(h.w));
  ((u16x4*)(oh + (size_t)row * DMODEL))[t] = h;
  ((u16x4*)(ol + (size_t)row * DMODEL))[t] = lo;
}

// ---------------- per-head rms + rope on q/k, split bf16 out; v split too ----
__global__ __launch_bounds__(256) void k_qkprep(const float* __restrict__ qkv,
                                                const float* __restrict__ cosb,
                                                const float* __restrict__ sinb,
                                                const float* __restrict__ qw,
                                                const float* __restrict__ kw,
                                                u16* __restrict__ qhh, u16* __restrict__ qll,
                                                u16* __restrict__ khh, u16* __restrict__ kll,
                                                u16* __restrict__ vhh, u16* __restrict__ vll) {
  int t = blockIdx.x;  // token
  int b = t / S_LEN, s = t - b * S_LEN;
  int wid = threadIdx.x >> 6, l = threadIdx.x & 63;
  const float* row = qkv + (size_t)t * 1536;
  float c = cosb[s * 64 + l], sn = sinb[s * 64 + l];
#pragma unroll
  for (int ii = 0; ii < 6; ii++) {
    int u = wid + 4 * ii;
    if (u < 16) {
      float v = row[u * 64 + l];
      float ss = wave_sum(v * v);
      float r = rsqrtf(ss * (1.0f / 64.0f) + EPSV);
      float vn = v * r * qw[l];
      float p = __shfl_xor(vn, 32);
      float o = (l < 32) ? (vn * c - p * sn) : (vn * c + p * sn);
      o *= 0.125f;  // 1/sqrt(HD) folded into q
      size_t base = (((size_t)(b * NH + u)) * S_LEN + s) * 64 + l;
      u16 hi = f2b(o);
      qhh[base] = hi; qll[base] = f2b(o - b2f(hi));
    } else if (u < 20) {
      int kv = u - 16;
      float v = row[1024 + kv * 64 + l];
      float ss = wave_sum(v * v);
      float r = rsqrtf(ss * (1.0f / 64.0f) + EPSV);
      float vn = v * r * kw[l];
      float p = __shfl_xor(vn, 32);
      float o = (l < 32) ? (vn * c - p * sn) : (vn * c + p * sn);
      size_t base = (((size_t)(b * NKV + kv)) * S_LEN + s) * 64 + l;
      u16 hi = f2b(o);
      khh[base] = hi; kll[base] = f2b(o - b2f(hi));
    } else {
      int kv = u - 20;
      float v = row[1280 + kv * 64 + l];
      size_t base = (((size_t)(b * NKV + kv)) * S_LEN + s) * 64 + l;
      u16 hi = f2b(v);
      vhh[base] = hi; vll[base] = f2b(v - b2f(hi));
    }
  }
}

// ---------------- transpose V: [g][s][64] -> [g][64][s] (bf16 hi/lo) --------
__global__ __launch_bounds__(256) void k_vtrans(const u16* __restrict__ vh,
                                                const u16* __restrict__ vl,
                                                u16* __restrict__ vth, u16* __restrict__ vtl) {
  int kb = blockIdx.x;  // key block of 128
  int gg = blockIdx.y;  // b*4+kv
  __shared__ u16 Th[128 * 64], Tl[128 * 64];
  int t = threadIdx.x;
  const u16* sh = vh + (((size_t)gg * S_LEN) + kb * 128) * 64;
  const u16* sl = vl + (((size_t)gg * S_LEN) + kb * 128) * 64;
#pragma unroll
  for (int p = 0; p < 8; p++) {
    int idx = p * 256 + t;
    int key = idx >> 4, dq = idx & 15;
    u16x4 a = *(const u16x4*)(sh + key * 64 + dq * 4);
    u16x4 bb = *(const u16x4*)(sl + key * 64 + dq * 4);
    int off = key * 128 + ((dq * 8) ^ ((key & 7) << 4));
    *(u16x4*)((char*)Th + off) = a;
    *(u16x4*)((char*)Tl + off) = bb;
  }
  __syncthreads();
  int d = t >> 2, kq = t & 3;
  u16 outh[32], outl[32];
#pragma unroll
  for (int jj = 0; jj < 32; jj++) {
    int key = kq * 32 + jj;
    int off = key * 128 + ((d * 2) ^ ((key & 7) << 4));
    outh[jj] = *(const u16*)((const char*)Th + off);
    outl[jj] = *(const u16*)((const char*)Tl + off);
  }
  u16* dsth = vth + (((size_t)gg * 64) + d) * S_LEN + kb * 128 + kq * 32;
  u16* dstl = vtl + (((size_t)gg * 64) + d) * S_LEN + kb * 128 + kq * 32;
#pragma unroll
  for (int q4 = 0; q4 < 8; q4++) {
    u16x4 a = {outh[q4 * 4], outh[q4 * 4 + 1], outh[q4 * 4 + 2], outh[q4 * 4 + 3]};
    u16x4 bb = {outl[q4 * 4], outl[q4 * 4 + 1], outl[q4 * 4 + 2], outl[q4 * 4 + 3]};
    *(u16x4*)(dsth + q4 * 4) = a;
    *(u16x4*)(dstl + q4 * 4) = bb;
  }
}

// ---------------- MFMA flash attention, split-precision ----------------
// block: (b,h, 64-query tile); 4 waves x 16 q-rows; 64-key chunks.
__global__ __launch_bounds__(256) void k_attn_mfma(
    const u16* __restrict__ qhp, const u16* __restrict__ qlp,
    const u16* __restrict__ khp, const u16* __restrict__ klp,
    const u16* __restrict__ vthp, const u16* __restrict__ vtlp,
    const float* __restrict__ sinks,
    u16* __restrict__ oh, u16* __restrict__ ol) {
  int qt = blockIdx.x;   // 0..31
  int bh = blockIdx.y;   // b*16+h
  int h = bh & 15, b = bh >> 4;
  int kvg = b * NKV + (h >> 2);
  int qbase = qt * 64;
  int t = threadIdx.x, w = t >> 6, l = t & 63;
  int g = l >> 4, li = l & 15;

  __shared__ u16 Qh[4096], Ql[4096], Kh[4096], Kl[4096], Vh[4096], Vl[4096];
  __shared__ u16 Ph[4][1024], Pl[4][1024];

  {
    const u16* sh = qhp + (((size_t)bh * S_LEN) + qbase) * 64;
    const u16* sl = qlp + (((size_t)bh * S_LEN) + qbase) * 64;
#pragma unroll
    for (int p = 0; p < 2; p++) {
      int idx = p * 256 + t;
      int row = idx >> 3, seg = idx & 7;
      u32x4 a = *(const u32x4*)(sh + row * 64 + seg * 8);
      u32x4 bb = *(const u32x4*)(sl + row * 64 + seg * 8);
      int off = row * 128 + ((seg * 16) ^ ((row & 7) << 4));
      *(u32x4*)((char*)Qh + off) = a;
      *(u32x4*)((char*)Ql + off) = bb;
    }
  }

  float m_[4], lsum[4];
  f32x4 accv[4];
  float sk = sinks[h];
#pragma unroll
  for (int j = 0; j < 4; j++) { m_[j] = sk; lsum[j] = 1.0f; }
#pragma unroll
  for (int nt = 0; nt < 4; nt++) accv[nt] = (f32x4){0.f, 0.f, 0.f, 0.f};

  int j0s = qbase - WINSZ; if (j0s < 0) j0s = 0;
  const u16* khb = khp + ((size_t)kvg * S_LEN) * 64;
  const u16* klb = klp + ((size_t)kvg * S_LEN) * 64;
  const u16* vthb = vthp + ((size_t)kvg * 64) * S_LEN;
  const u16* vtlb = vtlp + ((size_t)kvg * 64) * S_LEN;

  for (int j0 = j0s; j0 <= qbase; j0 += 64) {
    __syncthreads();
#pragma unroll
    for (int p = 0; p < 2; p++) {
      int idx = p * 256 + t;
      int row = idx >> 3, seg = idx & 7;
      int off = row * 128 + ((seg * 16) ^ ((row & 7) << 4));
      *(u32x4*)((char*)Kh + off) = *(const u32x4*)(khb + ((size_t)(j0 + row)) * 64 + seg * 8);
      *(u32x4*)((char*)Kl + off) = *(const u32x4*)(klb + ((size_t)(j0 + row)) * 64 + seg * 8);
      *(u32x4*)((char*)Vh + off) = *(const u32x4*)(vthb + (size_t)row * S_LEN + j0 + seg * 8);
      *(u32x4*)((char*)Vl + off) = *(const u32x4*)(vtlb + (size_t)row * S_LEN + j0 + seg * 8);
    }
    __syncthreads();

    f32x4 S[4];
#pragma unroll
    for (int nt = 0; nt < 4; nt++) S[nt] = (f32x4){0.f, 0.f, 0.f, 0.f};
#pragma unroll
    for (int ks = 0; ks < 2; ks++) {
      int arow = w * 16 + li;
      int coff = ks * 64 + g * 16;
      int ao = arow * 128 + (coff ^ ((arow & 7) << 4));
      bf16x8 qah = *(const bf16x8*)((char*)Qh + ao);
      bf16x8 qal = *(const bf16x8*)((char*)Ql + ao);
#pragma unroll
      for (int nt = 0; nt < 4; nt++) {
        int brow = nt * 16 + li;
        int bo = brow * 128 + (coff ^ ((brow & 7) << 4));
        bf16x8 kbh = *(const bf16x8*)((char*)Kh + bo);
        bf16x8 kbl = *(const bf16x8*)((char*)Kl + bo);
        S[nt] = __builtin_amdgcn_mfma_f32_16x16x32_bf16(qah, kbh, S[nt], 0, 0, 0);
        S[nt] = __builtin_amdgcn_mfma_f32_16x16x32_bf16(qah, kbl, S[nt], 0, 0, 0);
        S[nt] = __builtin_amdgcn_mfma_f32_16x16x32_bf16(qal, kbh, S[nt], 0, 0, 0);
      }
    }

    float scj[4];
#pragma unroll
    for (int j = 0; j < 4; j++) {
      int q = qbase + w * 16 + g * 4 + j;
      float sv[4];
      float mx = -1e30f;
#pragma unroll
      for (int nt = 0; nt < 4; nt++) {
        int key = j0 + nt * 16 + li;
        bool ok = (key <= q) && (key > q - WINSZ);
        sv[nt] = ok ? S[nt][j] : -1e30f;
        mx = fmaxf(mx, sv[nt]);
      }
#pragma unroll
      for (int o = 1; o < 16; o <<= 1) mx = fmaxf(mx, __shfl_xor(mx, o));
      float mn = fmaxf(m_[j], mx);
      float sc = __expf(m_[j] - mn);
      float ps = 0.f;
      float pv[4];
#pragma unroll
      for (int nt = 0; nt < 4; nt++) { pv[nt] = __expf(sv[nt] - mn); ps += pv[nt]; }
#pragma unroll
      for (int o = 1; o < 16; o <<= 1) ps += __shfl_xor(ps, o);
      lsum[j] = lsum[j] * sc + ps;
      m_[j] = mn;
      scj[j] = sc;
      int prow = g * 4 + j;
#pragma unroll
      for (int nt = 0; nt < 4; nt++) {
        int pb = prow * 128 + ((nt * 32 + li * 2) ^ ((prow & 7) << 4));
        u16 hi = f2b(pv[nt]);
        *(u16*)((char*)Ph[w] + pb) = hi;
        *(u16*)((char*)Pl[w] + pb) = f2b(pv[nt] - b2f(hi));
      }
    }
#pragma unroll
    for (int nt = 0; nt < 4; nt++) {
      f32x4 a = accv[nt];
      a[0] *= scj[0]; a[1] *= scj[1]; a[2] *= scj[2]; a[3] *= scj[3];
      accv[nt] = a;
    }

#pragma unroll
    for (int ks = 0; ks < 2; ks++) {
      int coff = ks * 64 + g * 16;
      int pb = li * 128 + (coff ^ ((li & 7) << 4));
      bf16x8 pah = *(const bf16x8*)((char*)Ph[w] + pb);
      bf16x8 pal = *(const bf16x8*)((char*)Pl[w] + pb);
#pragma unroll
      for (int nt = 0; nt < 4; nt++) {
        int vrow = nt * 16 + li;
        int vo = vrow * 128 + (coff ^ ((vrow & 7) << 4));
        bf16x8 vbh = *(const bf16x8*)((char*)Vh + vo);
        bf16x8 vbl = *(const bf16x8*)((char*)Vl + vo);
        accv[nt] = __builtin_amdgcn_mfma_f32_16x16x32_bf16(pah, vbh, accv[nt], 0, 0, 0);
        accv[nt] = __builtin_amdgcn_mfma_f32_16x16x32_bf16(pah, vbl, accv[nt], 0, 0, 0);
        accv[nt] = __builtin_amdgcn_mfma_f32_16x16x32_bf16(pal, vbh, accv[nt], 0, 0, 0);
      }
    }
  }

  float inv[4];
#pragma unroll
  for (int j = 0; j < 4; j++) inv[j] = 1.0f / lsum[j];
#pragma unroll
  for (int nt = 0; nt < 4; nt++) {
#pragma unroll
    for (int j = 0; j < 4; j++) {
      float o = accv[nt][j] * inv[j];
      int token = b * S_LEN + qbase + w * 16 + g * 4 + j;
      size_t off = (size_t)token * (NH * HDIM) + h * 64 + nt * 16 + li;
      u16 hi = f2b(o);
      oh[off] = hi;
      ol[off] = f2b(o - b2f(hi));
    }
  }
}

// ---------------- routing: rms(h1) -> m_b bf16, gate softmax top2, idx lists --
__global__ __launch_bounds__(256) void k_routing(const float* __restrict__ h1,
                                                 const float* __restrict__ pw,
                                                 const float* __restrict__ gw,
                                                 u16* __restrict__ mb, float* __restrict__ wd,
                                                 int* __restrict__ cnt, int* __restrict__ idxb) {
  int row = blockIdx.x;
  int t = threadIdx.x;
  int wid = t >> 6;
  const f32x4* xr = (const f32x4*)(h1 + (size_t)row * DMODEL);
  f32x4 v = xr[t];
  float ss = wave_sum(v.x * v.x + v.y * v.y + v.z * v.z + v.w * v.w);
  __shared__ float red[4];
  __shared__ float redp[4][4];
  if ((t & 63) == 0) red[wid] = ss;
  __syncthreads();
  float tot = red[0] + red[1] + red[2] + red[3];
  float r = rsqrtf(tot * (1.0f / DMODEL) + EPSV);
  f32x4 w4 = ((const f32x4*)pw)[t];
  float m0 = v.x * r * w4.x, m1 = v.y * r * w4.y, m2 = v.z * r * w4.z, m3 = v.w * r * w4.w;
  u16x4 hb; hb.x = f2b(m0); hb.y = f2b(m1); hb.z = f2b(m2); hb.w = f2b(m3);
  ((u16x4*)(mb + (size_t)row * DMODEL))[t] = hb;
#pragma unroll
  for (int e = 0; e < NEXP; e++) {
    f32x4 g4 = ((const f32x4*)(gw + (size_t)e * DMODEL))[t];
    float pe = wave_sum(m0 * g4.x + m1 * g4.y + m2 * g4.z + m3 * g4.w);
    if ((t & 63) == 0) redp[wid][e] = pe;
  }
  __syncthreads();
  if (t == 0) {
    float lg[4];
#pragma unroll
    for (int e = 0; e < NEXP; e++) lg[e] = redp[0][e] + redp[1][e] + redp[2][e] + redp[3][e];
    float mx = fmaxf(fmaxf(lg[0], lg[1]), fmaxf(lg[2], lg[3]));
    float ex[4], sm = 0.f;
#pragma unroll
    for (int e = 0; e < NEXP; e++) { ex[e] = expf(lg[e] - mx); sm += ex[e]; }
    int i1 = 0;
#pragma unroll
    for (int e = 1; e < NEXP; e++) if (lg[e] > lg[i1]) i1 = e;
    int i2 = -1;
#pragma unroll
    for (int e = 0; e < NEXP; e++) if (e != i1 && (i2 < 0 || lg[e] > lg[i2])) i2 = e;
    float p1 = ex[i1] / sm, p2 = ex[i2] / sm;
    float s2 = p1 + p2 + 1e-20f;
    float wrow[4] = {0.f, 0.f, 0.f, 0.f};
    wrow[i1] = p1 / s2; wrow[i2] = p2 / s2;
#pragma unroll
    for (int e = 0; e < NEXP; e++) wd[(size_t)row * NEXP + e] = wrow[e];
    int pos1 = atomicAdd(&cnt[i1], 1);
    idxb[i1 * NTOK + pos1] = row;
    int pos2 = atomicAdd(&cnt[i2], 1);
    idxb[i2 * NTOK + pos2] = row;
  }
}

// ---------------- MFMA GEMM: C[M,N] = A[M,K] @ Bw[N,K]^T ----------------
constexpr int EPI_STORE = 0;
constexpr int EPI_H1 = 1;
constexpr int EPI_G = 2;
constexpr int EPI_ACT = 3;
constexpr int EPI_DOWNM = 4;

template <int EPI, bool SPLIT>
__global__ __launch_bounds__(256) void k_gemm(
    const u16* __restrict__ Ah, const u16* __restrict__ Al,
    const u16* __restrict__ Bh, const u16* __restrict__ Bl,
    int M, int N, int K, int lda, int ldb,
    float* __restrict__ outF, int ldc, int col0,
    const float* __restrict__ addsrc,
    u16* __restrict__ outU, const u16* __restrict__ gsrc,
    const int* __restrict__ gidx, const int* __restrict__ cntp,
    int eid, const float* __restrict__ wdv) {
  constexpr int NSP = SPLIT ? 2 : 1;
  __shared__ u16 As[NSP * 128 * 32];
  __shared__ u16 Bs[NSP * 128 * 32];
  int tm = blockIdx.y, tn = blockIdx.x;
  int Meff = cntp ? *cntp : M;
  if (tm * 128 >= Meff) return;

  int t = threadIdx.x;
  int wid = t >> 6, l = t & 63;
  int wr = wid >> 1, wc = wid & 1;
  constexpr bool GA = (EPI == EPI_G || EPI == EPI_ACT);

  size_t a0off, a1off;
  if (GA && gidx) {
    int p0 = tm * 128 + (t >> 2);
    int p1 = p0 + 64;
    int t0 = (p0 < Meff) ? gidx[p0] : 0;
    int t1 = (p1 < Meff) ? gidx[p1] : 0;
    a0off = (size_t)t0 * lda + (t & 3) * 8;
    a1off = (size_t)t1 * lda + (t & 3) * 8;
  } else {
    a0off = (size_t)(tm * 128 + (t >> 2)) * lda + (t & 3) * 8;
    a1off = a0off + (size_t)64 * lda;
  }
  size_t b0off = (size_t)(tn * 128 + (t >> 2)) * ldb + (t & 3) * 8;
  size_t b1off = b0off + (size_t)64 * ldb;

  f32x4 acc[4][4];
#pragma unroll
  for (int i = 0; i < 4; i++)
#pragma unroll
    for (int j = 0; j < 4; j++) acc[i][j] = (f32x4){0.f, 0.f, 0.f, 0.f};

  int arow = wr * 64 + (l & 15);
  int brow = wc * 64 + (l & 15);
  int koff = (l >> 4) * 8;
  u32x4* As4 = (u32x4*)As;
  u32x4* Bs4 = (u32x4*)Bs;

  for (int k0 = 0; k0 < K; k0 += 32) {
    u32x4 va0 = *(const u32x4*)(Ah + a0off + k0);
    u32x4 va1 = *(const u32x4*)(Ah + a1off + k0);
    u32x4 vb0 = *(const u32x4*)(Bh + b0off + k0);
    u32x4 vb1 = *(const u32x4*)(Bh + b1off + k0);
    u32x4 va0l, va1l, vb0l, vb1l;
    if constexpr (SPLIT) {
      va0l = *(const u32x4*)(Al + a0off + k0);
      va1l = *(const u32x4*)(Al + a1off + k0);
      vb0l = *(const u32x4*)(Bl + b0off + k0);
      vb1l = *(const u32x4*)(Bl + b1off + k0);
    }
    __syncthreads();
    As4[t] = va0; As4[256 + t] = va1;
    Bs4[t] = vb0; Bs4[256 + t] = vb1;
    if constexpr (SPLIT) {
      As4[512 + t] = va0l; As4[768 + t] = va1l;
      Bs4[512 + t] = vb0l; Bs4[768 + t] = vb1l;
    }
    __syncthreads();
    bf16x8 af[NSP][4], bf[NSP][4];
#pragma unroll
    for (int mm = 0; mm < 4; mm++) {
      af[0][mm] = *(const bf16x8*)&As[(arow + mm * 16) * 32 + koff];
      bf[0][mm] = *(const bf16x8*)&Bs[(brow + mm * 16) * 32 + koff];
      if constexpr (SPLIT) {
        af[1][mm] = *(const bf16x8*)&As[128 * 32 + (arow + mm * 16) * 32 + koff];
        bf[1][mm] = *(const bf16x8*)&Bs[128 * 32 + (brow + mm * 16) * 32 + koff];
      }
    }
#pragma unroll
    for (int mi = 0; mi < 4; mi++)
#pragma unroll
      for (int ni = 0; ni < 4; ni++) {
        acc[mi][ni] = __builtin_amdgcn_mfma_f32_16x16x32_bf16(af[0][mi], bf[0][ni], acc[mi][ni], 0, 0, 0);
        if constexpr (SPLIT) {
          acc[mi][ni] = __builtin_amdgcn_mfma_f32_16x16x32_bf16(af[0][mi], bf[1][ni], acc[mi][ni], 0, 0, 0);
          acc[mi][ni] = __builtin_amdgcn_mfma_f32_16x16x32_bf16(af[1][mi], bf[0][ni], acc[mi][ni], 0, 0, 0);
        }
      }
  }

  int rb = tm * 128 + wr * 64 + ((l >> 4) << 2);
  int cb = tn * 128 + wc * 64 + (l & 15);
#pragma unroll
  for (int mi = 0; mi < 4; mi++) {
#pragma unroll
    for (int j = 0; j < 4; j++) {
      int r = rb + mi * 16 + j;
#pragma unroll
      for (int ni = 0; ni < 4; ni++) {
        int c = cb + ni * 16;
        float v = acc[mi][ni][j];
        if constexpr (EPI == EPI_STORE) {
          outF[(size_t)r * ldc + col0 + c] = v;
        } else if constexpr (EPI == EPI_H1) {
          size_t o = (size_t)r * ldc + c;
          outF[o] = v + addsrc[o];
        } else if constexpr (EPI == EPI_G) {
          outU[(size_t)r * N + c] = f2b(v);
        } else if constexpr (EPI == EPI_ACT) {
          float gv = b2f(gsrc[(size_t)r * N + c]);
          float gm = fminf(gv, LIMV);
          float um = fminf(fmaxf(v, -LIMV), LIMV);
          float a = gm / (1.0f + __expf(-gm)) * um;
          outU[(size_t)r * N + c] = f2b(a);
        } else {
          if (r < Meff) {
            int tok = gidx[r];
            float w = wdv[(size_t)tok * NEXP + eid];
            size_t o = (size_t)tok * ldc + c;
            outF[o] += w * v;
          }
        }
      }
    }
  }
}

// ---------------- final residual add ----------------
__global__ __launch_bounds__(256) void k_final(const float* __restrict__ h1,
                                               const float* __restrict__ y,
                                               float* __restrict__ out) {
  int i = blockIdx.x * 256 + threadIdx.x;
  f32x4 a = ((const f32x4*)h1)[i];
  f32x4 b = ((const f32x4*)y)[i];
  f32x4 r = {a.x + b.x, a.y + b.y, a.z + b.z, a.w + b.w};
  ((f32x4*)out)[i] = r;
}

// ---------------- host ----------------
extern "C" void kernel_launch(void* const* d_in, const int* in_sizes, int n_in,
                              void* d_out, int out_size, void* d_ws, size_t ws_size,
                              hipStream_t stream) {
  (void)in_sizes; (void)n_in; (void)out_size; (void)ws_size;
  const float* x = (const float*)d_in[0];
  const float* cosb = (const float*)d_in[1];
  const float* sinb = (const float*)d_in[2];
  const float* anw = (const float*)d_in[3];
  const float* pnw = (const float*)d_in[4];
  const float* qnw = (const float*)d_in[5];
  const float* knw = (const float*)d_in[6];
  const float* wq = (const float*)d_in[7];
  const float* wk = (const float*)d_in[8];
  const float* wv = (const float*)d_in[9];
  const float* wo = (const float*)d_in[10];
  const float* sinks = (const float*)d_in[11];
  const float* gw = (const float*)d_in[12];
  const float* egw = (const float*)d_in[13];
  const float* euw = (const float*)d_in[14];
  const float* edw = (const float*)d_in[15];
  const float* sgw = (const float*)d_in[16];
  const float* suw = (const float*)d_in[17];
  const float* sdw = (const float*)d_in[18];
  float* out = (float*)d_out;

  char* ws = (char*)d_ws;
  size_t off = 0;
  auto alloc = [&](size_t bytes) -> char* {
    char* p = ws + off;
    off += (bytes + 255) & ~(size_t)255;
    return p;
  };
  u16* wqh = (u16*)alloc(1048576 * 2); u16* wql = (u16*)alloc(1048576 * 2);
  u16* wkh = (u16*)alloc(262144 * 2);  u16* wkl = (u16*)alloc(262144 * 2);
  u16* wvh = (u16*)alloc(262144 * 2);  u16* wvl = (u16*)alloc(262144 * 2);
  u16* woh = (u16*)alloc(1048576 * 2); u16* wol = (u16*)alloc(1048576 * 2);
  u16* egb = (u16*)alloc((size_t)14680064 * 2);
  u16* eub = (u16*)alloc((size_t)14680064 * 2);
  u16* edb = (u16*)alloc((size_t)14680064 * 2);
  u16* sgb = (u16*)alloc((size_t)3670016 * 2);
  u16* sub = (u16*)alloc((size_t)3670016 * 2);
  u16* sdb = (u16*)alloc((size_t)3670016 * 2);
  u16* hinh = (u16*)alloc((size_t)NTOK * DMODEL * 2);
  u16* hinl = (u16*)alloc((size_t)NTOK * DMODEL * 2);
  u16* attnh = (u16*)alloc((size_t)NTOK * DMODEL * 2);
  u16* attnl = (u16*)alloc((size_t)NTOK * DMODEL * 2);
  float* h1 = (float*)alloc((size_t)NTOK * DMODEL * 4);
  u16* mb = (u16*)alloc((size_t)NTOK * DMODEL * 2);
  float* ybuf = (float*)alloc((size_t)NTOK * DMODEL * 4);
  float* wdbuf = (float*)alloc((size_t)NTOK * NEXP * 4);
  int* cnt = (int*)alloc(256);
  int* idxb = (int*)alloc((size_t)NEXP * NTOK * 4);
  // overlapped region: attention-path scratch then MoE scratch
  char* regA = alloc((size_t)58720256);
  float* qkvb = (float*)regA;                    // 4096 x 1536 fp32 (25165824 B)
  u16* qh_ = (u16*)(regA + 25165824);            // [B*H][S][64] bf16 hi (8388608)
  u16* ql_ = (u16*)(regA + 33554432);            // lo
  u16* kh_ = (u16*)(regA + 41943040);            // [B*KV][S][64] (2097152)
  u16* kl_ = (u16*)(regA + 44040192);
  u16* vh_ = (u16*)(regA + 46137344);
  u16* vl_ = (u16*)(regA + 48234496);
  u16* vth_ = (u16*)(regA + 50331648);           // [B*KV][64][S]
  u16* vtl_ = (u16*)(regA + 52428800);
  u16* gbuf = (u16*)regA;                        // MoE: 4096 x 3584 bf16
  u16* actb = (u16*)(regA + 29360128);

  k_init<<<1, 64, 0, stream>>>(cnt);

  CvtArgs ca;
  const float* srcs[10] = {wq, wk, wv, wo, egw, euw, edw, sgw, suw, sdw};
  u16* dhs[10] = {wqh, wkh, wvh, woh, egb, eub, edb, sgb, sub, sdb};
  u16* dls[10] = {wql, wkl, wvl, wol, nullptr, nullptr, nullptr, nullptr, nullptr, nullptr};
  int ns[10] = {1048576, 262144, 262144, 1048576, 14680064, 14680064, 14680064,
                3670016, 3670016, 3670016};
  for (int i = 0; i < 10; i++) {
    ca.src[i] = srcs[i]; ca.dh[i] = dhs[i]; ca.dl[i] = dls[i]; ca.n4[i] = ns[i] / 4;
  }
  k_convert<<<dim3(2048, 10), 256, 0, stream>>>(ca);

  k_rms_split<<<NTOK, 256, 0, stream>>>(x, anw, hinh, hinl);

  k_gemm<EPI_STORE, true><<<dim3(8, 32), 256, 0, stream>>>(
      hinh, hinl, wqh, wql, NTOK, 1024, 1024, 1024, 1024,
      qkvb, 1536, 0, nullptr, nullptr, nullptr, nullptr, nullptr, 0, nullptr);
  k_gemm<EPI_STORE, true><<<dim3(2, 32), 256, 0, stream>>>(
      hinh, hinl, wkh, wkl, NTOK, 256, 1024, 1024, 1024,
      qkvb, 1536, 1024, nullptr, nullptr, nullptr, nullptr, nullptr, 0, nullptr);
  k_gemm<EPI_STORE, true><<<dim3(2, 32), 256, 0, stream>>>(
      hinh, hinl, wvh, wvl, NTOK, 256, 1024, 1024, 1024,
      qkvb, 1536, 1280, nullptr, nullptr, nullptr, nullptr, nullptr, 0, nullptr);

  k_qkprep<<<NTOK, 256, 0, stream>>>(qkvb, cosb, sinb, qnw, knw,
                                     qh_, ql_, kh_, kl_, vh_, vl_);
  k_vtrans<<<dim3(16, 8), 256, 0, stream>>>(vh_, vl_, vth_, vtl_);
  k_attn_mfma<<<dim3(32, 32), 256, 0, stream>>>(qh_, ql_, kh_, kl_, vth_, vtl_,
                                                sinks, attnh, attnl);

  k_gemm<EPI_H1, true><<<dim3(8, 32), 256, 0, stream>>>(
      attnh, attnl, woh, wol, NTOK, 1024, 1024, 1024, 1024,
      h1, 1024, 0, x, nullptr, nullptr, nullptr, nullptr, 0, nullptr);

  k_routing<<<NTOK, 256, 0, stream>>>(h1, pnw, gw, mb, wdbuf, cnt, idxb);

  k_gemm<EPI_G, false><<<dim3(28, 32), 256, 0, stream>>>(
      mb, nullptr, sgb, nullptr, NTOK, IDIM, 1024, 1024, 1024,
      nullptr, 0, 0, nullptr, gbuf, nullptr, nullptr, nullptr, 0, nullptr);
  k_gemm<EPI_ACT, false><<<dim3(28, 32), 256, 0, stream>>>(
      mb, nullptr, sub, nullptr, NTOK, IDIM, 1024, 1024, 1024,
      nullptr, 0, 0, nullptr, actb, gbuf, nullptr, nullptr, 0, nullptr);
  k_gemm<EPI_STORE, false><<<dim3(8, 32), 256, 0, stream>>>(
      actb, nullptr, sdb, nullptr, NTOK, 1024, IDIM, IDIM, IDIM,
      ybuf, 1024, 0, nullptr, nullptr, nullptr, nullptr, nullptr, 0, nullptr);

  for (int e = 0; e < NEXP; e++) {
    const u16* beg = egb + (size_t)e * IDIM * DMODEL;
    const u16* beu = eub + (size_t)e * IDIM * DMODEL;
    const u16* bed = edb + (size_t)e * DMODEL * IDIM;
    k_gemm<EPI_G, false><<<dim3(28, 32), 256, 0, stream>>>(
        mb, nullptr, beg, nullptr, NTOK, IDIM, 1024, 1024, 1024,
        nullptr, 0, 0, nullptr, gbuf, nullptr, idxb + e * NTOK, cnt + e, e, nullptr);
    k_gemm<EPI_ACT, false><<<dim3(28, 32), 256, 0, stream>>>(
        mb, nullptr, beu, nullptr, NTOK, IDIM, 1024, 1024, 1024,
        nullptr, 0, 0, nullptr, actb, gbuf, idxb + e * NTOK, cnt + e, e, nullptr);
    k_gemm<EPI_DOWNM, false><<<dim3(8, 32), 256, 0, stream>>>(
        actb, nullptr, bed, nullptr, NTOK, 1024, IDIM, IDIM, IDIM,
        ybuf, 1024, 0, nullptr, nullptr, nullptr, idxb + e * NTOK, cnt + e, e, wdbuf);
  }

  k_final<<<4096, 256, 0, stream>>>(h1, ybuf, out);
}